// Round 2
// baseline (104.191 us; speedup 1.0000x reference)
//
#include <hip/hip_runtime.h>
#include <math.h>

#define NTILE 8
#define TS 64
#define T (NTILE * NTILE)
#define K 256
#define IMG_W (NTILE * TS)
#define PACK_STRIDE 12  // floats per packed gaussian slot (10 used, padded to 48B)

// Pass 1: gather + precompute per-(tile,k) packed gaussian data.
// slot = tile*K + k. Packed: [mux, muy, ea, eb, ed, lop, cr, cg, cb]
// Exponent is computed in base-2 with opacity folded in:
//   alpha_raw = op * exp(-0.5*maha) = exp2( ea*dx^2 + eb*dx*dy + ed*dy^2 + lop )
// maha = (d*dx^2 - (b+c)*dx*dy + a*dy^2)/det, so with s = -0.5*log2(e)/det:
//   ea = s*d,  eb = -s*(b+c),  ed = s*a,  lop = log2(op)
__global__ __launch_bounds__(256) void pack_kernel(
    const float* __restrict__ mu, const float* __restrict__ cov,
    const float* __restrict__ opacity, const float* __restrict__ color,
    const int* __restrict__ tile_idx, float* __restrict__ pack) {
  int slot = blockIdx.x * 256 + threadIdx.x;
  if (slot >= T * K) return;
  int n = tile_idx[slot];
  float a = cov[4 * n + 0];
  float b = cov[4 * n + 1];
  float c = cov[4 * n + 2];
  float d = cov[4 * n + 3];
  float det = fmaxf(a * d - b * c, 1e-6f);
  const float LOG2E = 1.4426950408889634f;
  float s = -0.5f * LOG2E / det;
  float* g = pack + (size_t)slot * PACK_STRIDE;
  g[0] = mu[2 * n + 0];
  g[1] = mu[2 * n + 1];
  g[2] = s * d;                         // ea
  g[3] = -s * (b + c);                  // eb
  g[4] = s * a;                         // ed
  g[5] = log2f(fmaxf(opacity[n], 1e-30f));  // lop
  g[6] = color[3 * n + 0];
  g[7] = color[3 * n + 1];
  g[8] = color[3 * n + 2];
}

// Pass 2: each thread renders TWO pixels in the same column (ly and ly+32),
// sharing dx-dependent terms and halving scalar-load waits per pixel.
// Per-k data pointer depends only on blockIdx => wave-uniform => s_load.
__global__ __launch_bounds__(256) void render_kernel(
    const float* __restrict__ pack, float* __restrict__ out) {
  int blk = blockIdx.x;           // 512 blocks: 8 per tile
  int tile = blk >> 3;
  int sub = blk & 7;              // row-group within tile
  int t = threadIdx.x;
  int lx = t & 63;
  int ly0 = sub * 4 + (t >> 6);   // 0..31
  int ty = tile >> 3;
  int tx = tile & 7;
  float px = (float)(tx * TS + lx) + 0.5f;
  float py0 = (float)(ty * TS + ly0) + 0.5f;

  const float* g0 = pack + (size_t)tile * K * PACK_STRIDE;
  float r0 = 0.0f, gg0 = 0.0f, b0 = 0.0f, S0 = 0.0f;
  float r1 = 0.0f, gg1 = 0.0f, b1 = 0.0f, S1 = 0.0f;

#pragma unroll 4
  for (int k = 0; k < K; ++k) {
    const float* g = g0 + k * PACK_STRIDE;
    float mux = g[0], muy = g[1];
    float ea = g[2], eb = g[3], ed = g[4], lop = g[5];
    float cr = g[6], cg = g[7], cb = g[8];
    float dx = px - mux;
    float dy0 = py0 - muy;
    float dy1 = dy0 + 32.0f;
    float q = ea * dx;
    float base = fmaf(q, dx, lop);  // ea*dx^2 + lop  (shared)
    float r = eb * dx;              // shared
    float m0 = fmaf(dy0, fmaf(ed, dy0, r), base);
    float m1 = fmaf(dy1, fmaf(ed, dy1, r), base);
    float a0 = fminf(fmaxf(exp2f(m0), 0.01f), 0.99f);  // v_med3
    float a1 = fminf(fmaxf(exp2f(m1), 0.01f), 0.99f);
    float w0 = fmaf(-a0, S0, a0);   // alpha*(1-S)
    float w1 = fmaf(-a1, S1, a1);
    r0 = fmaf(w0, cr, r0);
    gg0 = fmaf(w0, cg, gg0);
    b0 = fmaf(w0, cb, b0);
    r1 = fmaf(w1, cr, r1);
    gg1 = fmaf(w1, cg, gg1);
    b1 = fmaf(w1, cb, b1);
    S0 += a0;
    S1 += a1;
  }

  int x = tx * TS + lx;
  int y0 = ty * TS + ly0;
  size_t o0 = ((size_t)y0 * IMG_W + x) * 3;
  size_t o1 = ((size_t)(y0 + 32) * IMG_W + x) * 3;
  out[o0 + 0] = r0;
  out[o0 + 1] = gg0;
  out[o0 + 2] = b0;
  out[o1 + 0] = r1;
  out[o1 + 1] = gg1;
  out[o1 + 2] = b1;
}

// Fallback (only if ws_size is too small): stage per-tile data in LDS.
__global__ __launch_bounds__(256) void render_lds_kernel(
    const float* __restrict__ mu, const float* __restrict__ cov,
    const float* __restrict__ opacity, const float* __restrict__ color,
    const int* __restrict__ tile_idx, float* __restrict__ out) {
  __shared__ float4 sA[K];  // mux, muy, ea, eb
  __shared__ float4 sB[K];  // ed, lop, cr, cg
  __shared__ float sC[K];   // cb
  int blk = blockIdx.x;
  int tile = blk >> 3;
  int t = threadIdx.x;
  {
    int n = tile_idx[tile * K + t];
    float a = cov[4 * n + 0];
    float b = cov[4 * n + 1];
    float c = cov[4 * n + 2];
    float d = cov[4 * n + 3];
    float det = fmaxf(a * d - b * c, 1e-6f);
    const float LOG2E = 1.4426950408889634f;
    float s = -0.5f * LOG2E / det;
    sA[t] = make_float4(mu[2 * n], mu[2 * n + 1], s * d, -s * (b + c));
    sB[t] = make_float4(s * a, log2f(fmaxf(opacity[n], 1e-30f)),
                        color[3 * n], color[3 * n + 1]);
    sC[t] = color[3 * n + 2];
  }
  __syncthreads();

  int sub = blk & 7;
  int lx = t & 63;
  int ly0 = sub * 4 + (t >> 6);
  int ty = tile >> 3;
  int tx = tile & 7;
  float px = (float)(tx * TS + lx) + 0.5f;
  float py0 = (float)(ty * TS + ly0) + 0.5f;
  float r0 = 0.0f, gg0 = 0.0f, b0 = 0.0f, S0 = 0.0f;
  float r1 = 0.0f, gg1 = 0.0f, b1 = 0.0f, S1 = 0.0f;

#pragma unroll 4
  for (int k = 0; k < K; ++k) {
    float4 A = sA[k];
    float4 B = sB[k];
    float cb = sC[k];
    float dx = px - A.x;
    float dy0 = py0 - A.y;
    float dy1 = dy0 + 32.0f;
    float q = A.z * dx;
    float base = fmaf(q, dx, B.y);
    float r = A.w * dx;
    float m0 = fmaf(dy0, fmaf(B.x, dy0, r), base);
    float m1 = fmaf(dy1, fmaf(B.x, dy1, r), base);
    float a0 = fminf(fmaxf(exp2f(m0), 0.01f), 0.99f);
    float a1 = fminf(fmaxf(exp2f(m1), 0.01f), 0.99f);
    float w0 = fmaf(-a0, S0, a0);
    float w1 = fmaf(-a1, S1, a1);
    r0 = fmaf(w0, B.z, r0);
    gg0 = fmaf(w0, B.w, gg0);
    b0 = fmaf(w0, cb, b0);
    r1 = fmaf(w1, B.z, r1);
    gg1 = fmaf(w1, B.w, gg1);
    b1 = fmaf(w1, cb, b1);
    S0 += a0;
    S1 += a1;
  }

  int x = tx * TS + lx;
  int y0 = ty * TS + ly0;
  size_t o0 = ((size_t)y0 * IMG_W + x) * 3;
  size_t o1 = ((size_t)(y0 + 32) * IMG_W + x) * 3;
  out[o0 + 0] = r0;
  out[o0 + 1] = gg0;
  out[o0 + 2] = b0;
  out[o1 + 0] = r1;
  out[o1 + 1] = gg1;
  out[o1 + 2] = b1;
}

extern "C" void kernel_launch(void* const* d_in, const int* in_sizes, int n_in,
                              void* d_out, int out_size, void* d_ws,
                              size_t ws_size, hipStream_t stream) {
  const float* mu = (const float*)d_in[0];
  const float* cov = (const float*)d_in[1];
  const float* opacity = (const float*)d_in[2];
  const float* color = (const float*)d_in[3];
  const int* tile_idx = (const int*)d_in[4];
  float* out = (float*)d_out;

  const size_t need = (size_t)T * K * PACK_STRIDE * sizeof(float);  // 768 KB
  const int n_blocks = T * 8;  // 8 blocks per tile, 2 px/thread

  if (ws_size >= need) {
    float* pack = (float*)d_ws;
    pack_kernel<<<(T * K + 255) / 256, 256, 0, stream>>>(mu, cov, opacity,
                                                         color, tile_idx, pack);
    render_kernel<<<n_blocks, 256, 0, stream>>>(pack, out);
  } else {
    render_lds_kernel<<<n_blocks, 256, 0, stream>>>(mu, cov, opacity, color,
                                                    tile_idx, out);
  }
}

// Round 3
// 95.877 us; speedup vs baseline: 1.0867x; 1.0867x over previous
//
#include <hip/hip_runtime.h>
#include <math.h>

#define NTILE 8
#define TS 64
#define T (NTILE * NTILE)
#define K 256
#define KSEG (K / 2)
#define IMG_W (NTILE * TS)
#define PACK_STRIDE 12  // floats per packed gaussian slot (9 used, padded to 48B)

// Pass 1: gather + precompute per-(tile,k) packed gaussian data.
// slot = tile*K + k. Packed: [mux, muy, ea, eb, ed, lop, cr, cg, cb]
// alpha_raw = op*exp(-0.5*maha) = exp2(ea*dx^2 + eb*dx*dy + ed*dy^2 + lop)
// with s = -0.5*log2(e)/det: ea=s*d, eb=-s*(b+c), ed=s*a, lop=log2(op)
__global__ __launch_bounds__(256) void pack_kernel(
    const float* __restrict__ mu, const float* __restrict__ cov,
    const float* __restrict__ opacity, const float* __restrict__ color,
    const int* __restrict__ tile_idx, float* __restrict__ pack) {
  int slot = blockIdx.x * 256 + threadIdx.x;
  if (slot >= T * K) return;
  int n = tile_idx[slot];
  float a = cov[4 * n + 0];
  float b = cov[4 * n + 1];
  float c = cov[4 * n + 2];
  float d = cov[4 * n + 3];
  float det = fmaxf(a * d - b * c, 1e-6f);
  const float LOG2E = 1.4426950408889634f;
  float s = -0.5f * LOG2E / det;
  float* g = pack + (size_t)slot * PACK_STRIDE;
  g[0] = mu[2 * n + 0];
  g[1] = mu[2 * n + 1];
  g[2] = s * d;
  g[3] = -s * (b + c);
  g[4] = s * a;
  g[5] = log2f(fmaxf(opacity[n], 1e-30f));
  g[6] = color[3 * n + 0];
  g[7] = color[3 * n + 1];
  g[8] = color[3 * n + 2];
}

// Pass 2: 512-thread blocks; waves 0-3 (seg0) handle k=[0,128) for 256 pixels,
// waves 4-7 (seg1) handle k=[128,256) for the SAME 256 pixels.
// Linear decomposition of alpha compositing:
//   C = C0 + C1 - S0*A1, where A1 = sum(alpha_k*col_k) over seg1,
//   C1 computed with seg-local exclusive transmittance.
// Doubles wave parallelism (8192 waves -> 100% occupancy) to hide the
// scalar-load latency chain that pinned R1/R2 at ~41us.
__global__ __launch_bounds__(512, 8) void render_kernel(
    const float* __restrict__ pack, float* __restrict__ out) {
  __shared__ float sh[6][256];  // C1r,C1g,C1b,A1r,A1g,A1b per pixel

  int blk = blockIdx.x;   // 1024 blocks: 16 per tile
  int tile = blk >> 4;
  int chunk = blk & 15;
  int t = threadIdx.x;
  int p = t & 255;                 // pixel slot within chunk
  // Wave-uniform segment id (readfirstlane forces SGPR -> scalar k-loop loads)
  int seg = __builtin_amdgcn_readfirstlane(t) >> 8;

  int pp = chunk * 256 + p;        // pixel index within tile
  int ly = pp >> 6;
  int lx = pp & 63;
  int ty = tile >> 3;
  int tx = tile & 7;
  float px = (float)(tx * TS + lx) + 0.5f;
  float py = (float)(ty * TS + ly) + 0.5f;

  const float* g0 =
      pack + ((size_t)tile * K + (size_t)seg * KSEG) * PACK_STRIDE;

  float cr_a = 0.0f, cg_a = 0.0f, cb_a = 0.0f;  // C (seg-local compositing)
  float ar_a = 0.0f, ag_a = 0.0f, ab_a = 0.0f;  // A = sum alpha*col (seg1 only)
  float S = 0.0f;

  if (seg == 0) {
#pragma unroll 4
    for (int k = 0; k < KSEG; ++k) {
      const float* g = g0 + k * PACK_STRIDE;
      float mux = g[0], muy = g[1];
      float ea = g[2], eb = g[3], ed = g[4], lop = g[5];
      float cr = g[6], cg = g[7], cb = g[8];
      float dx = px - mux;
      float dy = py - muy;
      float base = fmaf(ea * dx, dx, lop);
      float m = fmaf(dy, fmaf(ed, dy, eb * dx), base);
      float a = fminf(fmaxf(__builtin_amdgcn_exp2f(m), 0.01f), 0.99f);
      float w = fmaf(-a, S, a);  // alpha*(1-S)
      cr_a = fmaf(w, cr, cr_a);
      cg_a = fmaf(w, cg, cg_a);
      cb_a = fmaf(w, cb, cb_a);
      S += a;
    }
  } else {
#pragma unroll 4
    for (int k = 0; k < KSEG; ++k) {
      const float* g = g0 + k * PACK_STRIDE;
      float mux = g[0], muy = g[1];
      float ea = g[2], eb = g[3], ed = g[4], lop = g[5];
      float cr = g[6], cg = g[7], cb = g[8];
      float dx = px - mux;
      float dy = py - muy;
      float base = fmaf(ea * dx, dx, lop);
      float m = fmaf(dy, fmaf(ed, dy, eb * dx), base);
      float a = fminf(fmaxf(__builtin_amdgcn_exp2f(m), 0.01f), 0.99f);
      float w = fmaf(-a, S, a);
      cr_a = fmaf(w, cr, cr_a);
      cg_a = fmaf(w, cg, cg_a);
      cb_a = fmaf(w, cb, cb_a);
      ar_a = fmaf(a, cr, ar_a);
      ag_a = fmaf(a, cg, ag_a);
      ab_a = fmaf(a, cb, ab_a);
      S += a;
    }
    sh[0][p] = cr_a;
    sh[1][p] = cg_a;
    sh[2][p] = cb_a;
    sh[3][p] = ar_a;
    sh[4][p] = ag_a;
    sh[5][p] = ab_a;
  }
  __syncthreads();
  if (seg == 0) {
    float fr = cr_a + sh[0][p] - S * sh[3][p];
    float fg = cg_a + sh[1][p] - S * sh[4][p];
    float fb = cb_a + sh[2][p] - S * sh[5][p];
    int x = tx * TS + lx;
    int y = ty * TS + ly;
    size_t o = ((size_t)y * IMG_W + x) * 3;
    out[o + 0] = fr;
    out[o + 1] = fg;
    out[o + 2] = fb;
  }
}

// Fallback (only if ws_size is too small): stage per-tile data in LDS.
__global__ __launch_bounds__(256) void render_lds_kernel(
    const float* __restrict__ mu, const float* __restrict__ cov,
    const float* __restrict__ opacity, const float* __restrict__ color,
    const int* __restrict__ tile_idx, float* __restrict__ out) {
  __shared__ float4 sA[K];
  __shared__ float4 sB[K];
  __shared__ float sC[K];
  int blk = blockIdx.x;
  int tile = blk >> 4;
  int t = threadIdx.x;
  {
    int n = tile_idx[tile * K + t];
    float a = cov[4 * n + 0];
    float b = cov[4 * n + 1];
    float c = cov[4 * n + 2];
    float d = cov[4 * n + 3];
    float det = fmaxf(a * d - b * c, 1e-6f);
    const float LOG2E = 1.4426950408889634f;
    float s = -0.5f * LOG2E / det;
    sA[t] = make_float4(mu[2 * n], mu[2 * n + 1], s * d, -s * (b + c));
    sB[t] = make_float4(s * a, log2f(fmaxf(opacity[n], 1e-30f)),
                        color[3 * n], color[3 * n + 1]);
    sC[t] = color[3 * n + 2];
  }
  __syncthreads();

  int chunk = blk & 15;
  int p = chunk * 256 + t;
  int ly = p >> 6;
  int lx = p & 63;
  int ty = tile >> 3;
  int tx = tile & 7;
  float px = (float)(tx * TS + lx) + 0.5f;
  float py = (float)(ty * TS + ly) + 0.5f;
  float accr = 0.0f, accg = 0.0f, accb = 0.0f, S = 0.0f;

#pragma unroll 4
  for (int k = 0; k < K; ++k) {
    float4 A = sA[k];
    float4 B = sB[k];
    float cb = sC[k];
    float dx = px - A.x;
    float dy = py - A.y;
    float base = fmaf(A.z * dx, dx, B.y);
    float m = fmaf(dy, fmaf(B.x, dy, A.w * dx), base);
    float a = fminf(fmaxf(__builtin_amdgcn_exp2f(m), 0.01f), 0.99f);
    float w = fmaf(-a, S, a);
    accr = fmaf(w, A.z * 0.0f + B.z, accr);  // B.z = cr
    accg = fmaf(w, B.w, accg);
    accb = fmaf(w, cb, accb);
    S += a;
  }

  int x = tx * TS + lx;
  int y = ty * TS + ly;
  size_t o = ((size_t)y * IMG_W + x) * 3;
  out[o + 0] = accr;
  out[o + 1] = accg;
  out[o + 2] = accb;
}

extern "C" void kernel_launch(void* const* d_in, const int* in_sizes, int n_in,
                              void* d_out, int out_size, void* d_ws,
                              size_t ws_size, hipStream_t stream) {
  const float* mu = (const float*)d_in[0];
  const float* cov = (const float*)d_in[1];
  const float* opacity = (const float*)d_in[2];
  const float* color = (const float*)d_in[3];
  const int* tile_idx = (const int*)d_in[4];
  float* out = (float*)d_out;

  const size_t need = (size_t)T * K * PACK_STRIDE * sizeof(float);  // 768 KB

  if (ws_size >= need) {
    float* pack = (float*)d_ws;
    pack_kernel<<<(T * K + 255) / 256, 256, 0, stream>>>(mu, cov, opacity,
                                                         color, tile_idx, pack);
    render_kernel<<<T * 16, 512, 0, stream>>>(pack, out);
  } else {
    render_lds_kernel<<<T * 16, 256, 0, stream>>>(mu, cov, opacity, color,
                                                  tile_idx, out);
  }
}

// Round 4
// 88.189 us; speedup vs baseline: 1.1815x; 1.0872x over previous
//
#include <hip/hip_runtime.h>
#include <math.h>

#define NTILE 8
#define TS 64
#define T 64
#define K 256
#define NSEG 4
#define KSEG 64
#define IMG_W 512

// 32-byte packed gaussian record -> one s_load_dwordx8 per k-iteration.
// Colors stored as bf16 (decoded with wave-uniform scalar shifts, ~free).
struct __align__(32) Rec {
  float mux, muy, ea, eb, ed, lop;
  unsigned crcg;  // bf16(cr) | bf16(cg)<<16
  unsigned cbu;   // bf16(cb)
};

__device__ inline unsigned bf16r(float x) {
  return (__float_as_uint(x) + 0x8000u) >> 16;  // round-to-nearest-ish
}

// Pass 1: one block per tile (block b -> XCD b%8, matching render's tile->XCD
// mapping so pack data stays in the local XCD L2).
// alpha_raw = op*exp(-0.5*maha) = exp2(ea*dx^2 + eb*dx*dy + ed*dy^2 + lop),
// s = -0.5*log2(e)/det: ea=s*d, eb=-s*(b+c), ed=s*a, lop=log2(op).
__global__ __launch_bounds__(256) void pack_kernel(
    const float* __restrict__ mu, const float* __restrict__ cov,
    const float* __restrict__ opacity, const float* __restrict__ color,
    const int* __restrict__ tile_idx, Rec* __restrict__ pack) {
  int tile = blockIdx.x;  // 64 blocks
  int k = threadIdx.x;
  int slot = tile * K + k;
  int n = tile_idx[slot];
  float a = cov[4 * n + 0];
  float b = cov[4 * n + 1];
  float c = cov[4 * n + 2];
  float d = cov[4 * n + 3];
  float det = fmaxf(a * d - b * c, 1e-6f);
  const float LOG2E = 1.4426950408889634f;
  float s = -0.5f * LOG2E / det;
  Rec r;
  r.mux = mu[2 * n + 0];
  r.muy = mu[2 * n + 1];
  r.ea = s * d;
  r.eb = -s * (b + c);
  r.ed = s * a;
  r.lop = log2f(fmaxf(opacity[n], 1e-30f));
  r.crcg = bf16r(color[3 * n + 0]) | (bf16r(color[3 * n + 1]) << 16);
  r.cbu = bf16r(color[3 * n + 2]);
  pack[slot] = r;
}

// Pass 2: 1024 blocks x 512 threads. Within a block: seg = tid>>7 (0..3),
// each seg handles k=[seg*64, seg*64+64) for the same 256 pixels; each
// thread renders 2 pixels sharing the dx column terms (rows ly and ly+2).
// Linear segment combine: C = sum_s (C_s_local - S_prev * A_s),
//   A_s = sum alpha_k*col_k, S_prev = sum of earlier segs' alpha sums.
__global__ __launch_bounds__(512, 8) void render_kernel(
    const Rec* __restrict__ pack, float* __restrict__ out) {
  __shared__ float sS[NSEG][128][2];  // per-seg alpha sums, 2 px/thread
  __shared__ float sD[3][128][6];     // segs 1..3 final contributions

  int blk = blockIdx.x;
  int tile = blk & 63;   // XCD affinity: tile%8 == blk%8
  int chunk = blk >> 6;  // 0..15, 4 pixel-rows each
  int tid = threadIdx.x;
  int seg = __builtin_amdgcn_readfirstlane(tid) >> 7;  // wave-uniform
  int pslot = tid & 127;
  int lx = pslot & 63;
  int lrow = pslot >> 6;  // 0..1; pixel pair = rows lrow and lrow+2 of chunk
  int ty = tile >> 3, tx = tile & 7;
  int ly0 = chunk * 4 + lrow;
  float px = (float)(tx * TS + lx) + 0.5f;
  float py0 = (float)(ty * TS + ly0) + 0.5f;  // py1 = py0 + 2

  const Rec* g0 = pack + (size_t)tile * K + (size_t)seg * KSEG;

  float c0r = 0, c0g = 0, c0b = 0, c1r = 0, c1g = 0, c1b = 0;
  float a0r = 0, a0g = 0, a0b = 0, a1r = 0, a1g = 0, a1b = 0;
  float S0 = 0, S1 = 0;

  if (seg == 0) {
#pragma unroll 8
    for (int k = 0; k < KSEG; ++k) {
      const Rec* g = g0 + k;
      float mux = g->mux, muy = g->muy;
      float ea = g->ea, eb = g->eb, ed = g->ed, lop = g->lop;
      unsigned crcg = g->crcg, cbu = g->cbu;
      float cr = __uint_as_float(crcg << 16);
      float cg = __uint_as_float(crcg & 0xffff0000u);
      float cb = __uint_as_float(cbu << 16);
      float dx = px - mux;
      float tb = eb * dx;
      float base = fmaf(ea * dx, dx, lop);
      float dy0 = py0 - muy;
      float dy1 = dy0 + 2.0f;
      float m0 = fmaf(dy0, fmaf(ed, dy0, tb), base);
      float m1 = fmaf(dy1, fmaf(ed, dy1, tb), base);
      float al0 = fminf(fmaxf(__builtin_amdgcn_exp2f(m0), 0.01f), 0.99f);
      float al1 = fminf(fmaxf(__builtin_amdgcn_exp2f(m1), 0.01f), 0.99f);
      float w0 = fmaf(-al0, S0, al0);
      float w1 = fmaf(-al1, S1, al1);
      c0r = fmaf(w0, cr, c0r);
      c0g = fmaf(w0, cg, c0g);
      c0b = fmaf(w0, cb, c0b);
      c1r = fmaf(w1, cr, c1r);
      c1g = fmaf(w1, cg, c1g);
      c1b = fmaf(w1, cb, c1b);
      S0 += al0;
      S1 += al1;
    }
  } else {
#pragma unroll 8
    for (int k = 0; k < KSEG; ++k) {
      const Rec* g = g0 + k;
      float mux = g->mux, muy = g->muy;
      float ea = g->ea, eb = g->eb, ed = g->ed, lop = g->lop;
      unsigned crcg = g->crcg, cbu = g->cbu;
      float cr = __uint_as_float(crcg << 16);
      float cg = __uint_as_float(crcg & 0xffff0000u);
      float cb = __uint_as_float(cbu << 16);
      float dx = px - mux;
      float tb = eb * dx;
      float base = fmaf(ea * dx, dx, lop);
      float dy0 = py0 - muy;
      float dy1 = dy0 + 2.0f;
      float m0 = fmaf(dy0, fmaf(ed, dy0, tb), base);
      float m1 = fmaf(dy1, fmaf(ed, dy1, tb), base);
      float al0 = fminf(fmaxf(__builtin_amdgcn_exp2f(m0), 0.01f), 0.99f);
      float al1 = fminf(fmaxf(__builtin_amdgcn_exp2f(m1), 0.01f), 0.99f);
      float w0 = fmaf(-al0, S0, al0);
      float w1 = fmaf(-al1, S1, al1);
      c0r = fmaf(w0, cr, c0r);
      c0g = fmaf(w0, cg, c0g);
      c0b = fmaf(w0, cb, c0b);
      c1r = fmaf(w1, cr, c1r);
      c1g = fmaf(w1, cg, c1g);
      c1b = fmaf(w1, cb, c1b);
      a0r = fmaf(al0, cr, a0r);
      a0g = fmaf(al0, cg, a0g);
      a0b = fmaf(al0, cb, a0b);
      a1r = fmaf(al1, cr, a1r);
      a1g = fmaf(al1, cg, a1g);
      a1b = fmaf(al1, cb, a1b);
      S0 += al0;
      S1 += al1;
    }
  }

  sS[seg][pslot][0] = S0;
  sS[seg][pslot][1] = S1;
  __syncthreads();

  float Sp0 = 0.f, Sp1 = 0.f;
  if (seg >= 1) { Sp0 += sS[0][pslot][0]; Sp1 += sS[0][pslot][1]; }
  if (seg >= 2) { Sp0 += sS[1][pslot][0]; Sp1 += sS[1][pslot][1]; }
  if (seg >= 3) { Sp0 += sS[2][pslot][0]; Sp1 += sS[2][pslot][1]; }
  if (seg >= 1) {
    sD[seg - 1][pslot][0] = fmaf(-Sp0, a0r, c0r);
    sD[seg - 1][pslot][1] = fmaf(-Sp0, a0g, c0g);
    sD[seg - 1][pslot][2] = fmaf(-Sp0, a0b, c0b);
    sD[seg - 1][pslot][3] = fmaf(-Sp1, a1r, c1r);
    sD[seg - 1][pslot][4] = fmaf(-Sp1, a1g, c1g);
    sD[seg - 1][pslot][5] = fmaf(-Sp1, a1b, c1b);
  }
  __syncthreads();

  if (seg == 0) {
    float f0r = c0r + sD[0][pslot][0] + sD[1][pslot][0] + sD[2][pslot][0];
    float f0g = c0g + sD[0][pslot][1] + sD[1][pslot][1] + sD[2][pslot][1];
    float f0b = c0b + sD[0][pslot][2] + sD[1][pslot][2] + sD[2][pslot][2];
    float f1r = c1r + sD[0][pslot][3] + sD[1][pslot][3] + sD[2][pslot][3];
    float f1g = c1g + sD[0][pslot][4] + sD[1][pslot][4] + sD[2][pslot][4];
    float f1b = c1b + sD[0][pslot][5] + sD[1][pslot][5] + sD[2][pslot][5];
    int x = tx * TS + lx;
    int y0 = ty * TS + ly0;
    size_t o0 = ((size_t)y0 * IMG_W + x) * 3;
    size_t o1 = o0 + (size_t)2 * IMG_W * 3;  // row ly0+2
    out[o0 + 0] = f0r;
    out[o0 + 1] = f0g;
    out[o0 + 2] = f0b;
    out[o1 + 0] = f1r;
    out[o1 + 1] = f1g;
    out[o1 + 2] = f1b;
  }
}

// Fallback only if ws_size < 512 KB (never expected to run on this harness).
__global__ __launch_bounds__(256) void render_lds_kernel(
    const float* __restrict__ mu, const float* __restrict__ cov,
    const float* __restrict__ opacity, const float* __restrict__ color,
    const int* __restrict__ tile_idx, float* __restrict__ out) {
  __shared__ float4 sA[K];
  __shared__ float4 sB[K];
  __shared__ float sC[K];
  int blk = blockIdx.x;
  int tile = blk >> 4;
  int t = threadIdx.x;
  {
    int n = tile_idx[tile * K + t];
    float a = cov[4 * n + 0];
    float b = cov[4 * n + 1];
    float c = cov[4 * n + 2];
    float d = cov[4 * n + 3];
    float det = fmaxf(a * d - b * c, 1e-6f);
    const float LOG2E = 1.4426950408889634f;
    float s = -0.5f * LOG2E / det;
    sA[t] = make_float4(mu[2 * n], mu[2 * n + 1], s * d, -s * (b + c));
    sB[t] = make_float4(s * a, log2f(fmaxf(opacity[n], 1e-30f)),
                        color[3 * n], color[3 * n + 1]);
    sC[t] = color[3 * n + 2];
  }
  __syncthreads();
  int chunk = blk & 15;
  int p = chunk * 256 + t;
  int ly = p >> 6;
  int lx = p & 63;
  int ty = tile >> 3;
  int tx = tile & 7;
  float px = (float)(tx * TS + lx) + 0.5f;
  float py = (float)(ty * TS + ly) + 0.5f;
  float accr = 0.0f, accg = 0.0f, accb = 0.0f, S = 0.0f;
#pragma unroll 4
  for (int k = 0; k < K; ++k) {
    float4 A = sA[k];
    float4 B = sB[k];
    float cb = sC[k];
    float dx = px - A.x;
    float dy = py - A.y;
    float base = fmaf(A.z * dx, dx, B.y);
    float m = fmaf(dy, fmaf(B.x, dy, A.w * dx), base);
    float a = fminf(fmaxf(__builtin_amdgcn_exp2f(m), 0.01f), 0.99f);
    float w = fmaf(-a, S, a);
    accr = fmaf(w, B.z, accr);
    accg = fmaf(w, B.w, accg);
    accb = fmaf(w, cb, accb);
    S += a;
  }
  int x = tx * TS + lx;
  int y = ty * TS + ly;
  size_t o = ((size_t)y * IMG_W + x) * 3;
  out[o + 0] = accr;
  out[o + 1] = accg;
  out[o + 2] = accb;
}

extern "C" void kernel_launch(void* const* d_in, const int* in_sizes, int n_in,
                              void* d_out, int out_size, void* d_ws,
                              size_t ws_size, hipStream_t stream) {
  const float* mu = (const float*)d_in[0];
  const float* cov = (const float*)d_in[1];
  const float* opacity = (const float*)d_in[2];
  const float* color = (const float*)d_in[3];
  const int* tile_idx = (const int*)d_in[4];
  float* out = (float*)d_out;

  const size_t need = (size_t)T * K * sizeof(Rec);  // 512 KB

  if (ws_size >= need) {
    Rec* pack = (Rec*)d_ws;
    pack_kernel<<<T, 256, 0, stream>>>(mu, cov, opacity, color, tile_idx,
                                       pack);
    render_kernel<<<T * 16, 512, 0, stream>>>(pack, out);
  } else {
    render_lds_kernel<<<T * 16, 256, 0, stream>>>(mu, cov, opacity, color,
                                                  tile_idx, out);
  }
}